// Round 4
// baseline (624.963 us; speedup 1.0000x reference)
//
#include <hip/hip_runtime.h>
#include <math.h>

#define B_ 8
#define N_ 4096
#define D_ 768
#define H_ 8
#define HD_ 96
#define FG_ 2049
#define TWO_PI 6.283185307179586476925f
// XOR bank swizzle for float2 LDS array: bijective involution, no padding.
#define SWZ(i) ((i) ^ (((i) >> 4) & 15))

// Abramowitz-Stegun 7.1.26: |err| <= 1.5e-7, much cheaper than libm erff.
__device__ __forceinline__ float erf_fast(float x) {
    float ax = fabsf(x);
    float t = __builtin_amdgcn_rcpf(fmaf(0.3275911f, ax, 1.0f));
    float p = fmaf(fmaf(fmaf(fmaf(1.061405429f, t, -1.453152027f), t, 1.421413741f),
                        t, -0.284496736f), t, 0.254829592f) * t;
    float r = 1.0f - p * __expf(-ax * ax);
    return copysignf(r, x);
}

__device__ __forceinline__ float gelu_f(float x) {
    return 0.5f * x * (1.0f + erf_fast(x * 0.7071067811865475f));
}

// base-4 digit reversal of a 12-bit index (involution)
__device__ __forceinline__ int rev4_12(int x) {
    int r = (int)(__brev((unsigned)x) >> 20);
    return ((r & 0x555) << 1) | ((r >> 1) & 0x555);
}

// One-time init: twiddles, Hann, ctx zero, ag/al/h1g/h1l bias init.
__global__ void k_init(const float* __restrict__ b2g, const float* __restrict__ b2l,
                       const float* __restrict__ b1g, const float* __restrict__ b1l,
                       float2* __restrict__ twg, float* __restrict__ hanng,
                       float* __restrict__ ctx, float* __restrict__ ag,
                       float* __restrict__ al, float* __restrict__ h1g,
                       float* __restrict__ h1l) {
    int i = blockIdx.x * 256 + threadIdx.x;
    if (i < 2048) {
        float s, c;
        sincosf(-TWO_PI * (float)i / 4096.0f, &s, &c);
        twg[i] = make_float2(c, s);
    }
    if (i < 4096) hanng[i] = 0.5f - 0.5f * cosf(TWO_PI * (float)i / 4095.0f);
    if (i < B_ * D_) ctx[i] = 0.f;
    if (i < 768) {
        float vg = b1g[i], vl = b1l[i];
        for (int b = 0; b < B_; ++b) {
            h1g[b * 768 + i] = vg;
            h1l[b * 768 + i] = vl;
        }
    }
    const int CG = H_ * FG_ * 2;  // 32784
    if (i < CG) {
        float v = b2g[i];
        for (int b = 0; b < B_; ++b) ag[(size_t)b * CG + i] = v;
    } else if (i < CG + 80) {
        int cc = i - CG;
        float v = b2l[cc];
        for (int b = 0; b < B_; ++b) al[b * 80 + cc] = v;
    }
}

// Wave-per-row LayerNorm stats: mu, rstd per (b,n) row. 4 waves/block.
__global__ __launch_bounds__(256) void k_stats(const float* __restrict__ x,
                                               float* __restrict__ mu,
                                               float* __restrict__ rstd) {
    int row = blockIdx.x * 4 + (threadIdx.x >> 6);
    int lane = threadIdx.x & 63;
    const float4* xr = (const float4*)(x + (size_t)row * D_);
    float4 a = xr[lane], b = xr[lane + 64], c = xr[lane + 128];
    float s = a.x + a.y + a.z + a.w + b.x + b.y + b.z + b.w + c.x + c.y + c.z + c.w;
    #pragma unroll
    for (int o = 32; o > 0; o >>= 1) s += __shfl_xor(s, o);
    float m = s * (1.0f / 768.0f);
    float v = 0.f, d;
    d = a.x - m; v += d * d; d = a.y - m; v += d * d;
    d = a.z - m; v += d * d; d = a.w - m; v += d * d;
    d = b.x - m; v += d * d; d = b.y - m; v += d * d;
    d = b.z - m; v += d * d; d = b.w - m; v += d * d;
    d = c.x - m; v += d * d; d = c.y - m; v += d * d;
    d = c.z - m; v += d * d; d = c.w - m; v += d * d;
    #pragma unroll
    for (int o = 32; o > 0; o >>= 1) v += __shfl_xor(v, o);
    if (lane == 0) {
        mu[row] = m;
        rstd[row] = rsqrtf(v * (1.0f / 768.0f) + 1e-5f);
    }
}

// Fused: normalize + transposed write [B][D][N] + ctx partial sums (atomics).
__global__ __launch_bounds__(256) void k_lnT(const float* __restrict__ x,
                                             const float* __restrict__ mu,
                                             const float* __restrict__ rstd,
                                             const float* __restrict__ lw,
                                             const float* __restrict__ lb,
                                             float* __restrict__ xt,
                                             float* __restrict__ ctx) {
    __shared__ float tile[64][65];
    __shared__ float csum[4][64];
    int d0 = blockIdx.x * 64, n0 = blockIdx.y * 64, b = blockIdx.z;
    int c = threadIdx.x & 63, r4 = threadIdx.x >> 6;
    float w = lw[d0 + c], bias = lb[d0 + c];
    float partial = 0.f;
    #pragma unroll
    for (int q = 0; q < 16; ++q) {
        int r = r4 * 16 + q;
        int row = b * N_ + n0 + r;
        float v = (x[(size_t)row * D_ + d0 + c] - mu[row]) * rstd[row] * w + bias;
        tile[r][c] = v;
        partial += v;
    }
    csum[r4][c] = partial;
    __syncthreads();
    if (r4 == 0)
        atomicAdd(ctx + b * D_ + d0 + c,
                  (csum[0][c] + csum[1][c] + csum[2][c] + csum[3][c]) * (1.0f / 4096.0f));
    #pragma unroll
    for (int q = 0; q < 16; ++q) {
        int r = r4 * 16 + q;  // d-row
        xt[((size_t)b * D_ + d0 + r) * N_ + n0 + c] = tile[c][r];
    }
}

// Split-K pre-activation MLP1: h1g/h1l += ctx@w1 chunk (bias pre-init in k_init,
// gelu applied in k_mlp2 staging). hf computed full-depth by dedicated blocks.
__global__ void k_mlp1(const float* __restrict__ ctx,
                       const float* __restrict__ w1g, const float* __restrict__ w1l,
                       const float* __restrict__ wf1, const float* __restrict__ bf1,
                       float* __restrict__ h1g, float* __restrict__ h1l,
                       float* __restrict__ hf) {
    int t = threadIdx.x, xb = blockIdx.x, y = blockIdx.y;
    float acc[B_];
    #pragma unroll
    for (int b = 0; b < B_; ++b) acc[b] = 0.f;
    if (y < 8) {
        int c = xb * 256 + t;
        if (c >= 1536) return;
        const float* w = (c < 768) ? w1g : w1l;
        float* out = (c < 768) ? h1g : h1l;
        int cc = (c < 768) ? c : c - 768;
        int d0 = y * 96;
        for (int d = 0; d < 96; ++d) {
            float wv = w[(size_t)(d0 + d) * 768 + cc];
            #pragma unroll
            for (int b = 0; b < B_; ++b) acc[b] += ctx[b * 768 + d0 + d] * wv;
        }
        for (int b = 0; b < B_; ++b) atomicAdd(out + b * 768 + cc, acc[b]);
    } else {
        if (xb < 6) return;
        int cc = (xb - 6) * 256 + t;
        if (cc >= 384) return;
        for (int d = 0; d < 768; ++d) {
            float wv = wf1[(size_t)d * 384 + cc];
            #pragma unroll
            for (int b = 0; b < B_; ++b) acc[b] += ctx[b * 768 + d] * wv;
        }
        float bv = bf1[cc];
        for (int b = 0; b < B_; ++b) hf[b * 384 + cc] = gelu_f(acc[b] + bv);
    }
}

// split-K (8 chunks of 96): ag += gelu(h1g)@w2g chunk; al += gelu(h1l)@w2l; gate.
__global__ void k_mlp2(const float* __restrict__ h1g, const float* __restrict__ h1l,
                       const float* __restrict__ hf,
                       const float* __restrict__ w2g, const float* __restrict__ w2l,
                       const float* __restrict__ wf2, const float* __restrict__ bf2,
                       float* __restrict__ ag, float* __restrict__ al, float* __restrict__ gate) {
    int kc = blockIdx.y;       // 0..7
    int d0 = kc * 96;
    __shared__ float lg[B_ * 96];
    __shared__ float ll[B_ * 96];
    for (int i = threadIdx.x; i < B_ * 96; i += 256) {
        int bb = i / 96, dd = i % 96;
        lg[i] = gelu_f(h1g[bb * 768 + d0 + dd]);
        ll[i] = gelu_f(h1l[bb * 768 + d0 + dd]);
    }
    __syncthreads();
    int c = blockIdx.x * 256 + threadIdx.x;
    const int CG = H_ * FG_ * 2;  // 32784
    float acc[B_];
    #pragma unroll
    for (int b = 0; b < B_; ++b) acc[b] = 0.f;
    if (c < CG) {
        for (int d = 0; d < 96; ++d) {
            float wv = w2g[(size_t)(d0 + d) * CG + c];
            #pragma unroll
            for (int b = 0; b < B_; ++b) acc[b] += lg[b * 96 + d] * wv;
        }
        for (int b = 0; b < B_; ++b) atomicAdd(ag + (size_t)b * CG + c, acc[b]);
    } else if (c < CG + 80) {
        int cc = c - CG;
        for (int d = 0; d < 96; ++d) {
            float wv = w2l[(d0 + d) * 80 + cc];
            #pragma unroll
            for (int b = 0; b < B_; ++b) acc[b] += ll[b * 96 + d] * wv;
        }
        for (int b = 0; b < B_; ++b) atomicAdd(al + b * 80 + cc, acc[b]);
    } else if (c < CG + 88 && kc == 0) {
        int cc = c - CG - 80;
        for (int d = 0; d < 384; ++d) {
            float wv = wf2[d * 8 + cc];
            #pragma unroll
            for (int b = 0; b < B_; ++b) acc[b] += hf[b * 384 + d] * wv;
        }
        for (int b = 0; b < B_; ++b)
            gate[b * 8 + cc] = 1.0f / (1.0f + expf(-(acc[b] + bf2[cc])));
    }
}

// ---- radix-4 DIT stage, FORWARD (twiddles on inputs, -i combine). ----
template<int LQ>
__device__ __forceinline__ void dit_stage_f(float2* z, const float2* __restrict__ twg, int t) {
    const int Q = 1 << LQ;
    #pragma unroll
    for (int u = 0; u < 4; ++u) {
        int j = t + (u << 8);
        int pos = j & (Q - 1);
        int i0 = ((j >> LQ) << (LQ + 2)) + pos;
        int p0 = SWZ(i0), p1 = SWZ(i0 + Q), p2 = SWZ(i0 + 2 * Q), p3 = SWZ(i0 + 3 * Q);
        float2 a = z[p0], b = z[p1], c = z[p2], d = z[p3];
        float2 w1 = twg[pos << (10 - LQ)];
        float2 w2 = make_float2(w1.x * w1.x - w1.y * w1.y, 2.f * w1.x * w1.y);
        float2 w3 = make_float2(w1.x * w2.x - w1.y * w2.y, w1.x * w2.y + w1.y * w2.x);
        float2 bh = make_float2(b.x * w1.x - b.y * w1.y, b.x * w1.y + b.y * w1.x);
        float2 ch = make_float2(c.x * w2.x - c.y * w2.y, c.x * w2.y + c.y * w2.x);
        float2 dh = make_float2(d.x * w3.x - d.y * w3.y, d.x * w3.y + d.y * w3.x);
        float t0x = a.x + ch.x,  t0y = a.y + ch.y;
        float t1x = a.x - ch.x,  t1y = a.y - ch.y;
        float t2x = bh.x + dh.x, t2y = bh.y + dh.y;
        float t3x = bh.x - dh.x, t3y = bh.y - dh.y;
        z[p0] = make_float2(t0x + t2x, t0y + t2y);
        z[p1] = make_float2(t1x + t3y, t1y - t3x);   // t1 - i*t3
        z[p2] = make_float2(t0x - t2x, t0y - t2y);
        z[p3] = make_float2(t1x - t3y, t1y + t3x);   // t1 + i*t3
    }
}

// ---- radix-4 DIF stage, INVERSE (conj twiddles on outputs, +i combine). ----
template<int LQ>
__device__ __forceinline__ void dif_stage_i(float2* z, const float2* __restrict__ twg, int t) {
    const int Q = 1 << LQ;
    #pragma unroll
    for (int u = 0; u < 4; ++u) {
        int j = t + (u << 8);
        int pos = j & (Q - 1);
        int i0 = ((j >> LQ) << (LQ + 2)) + pos;
        int p0 = SWZ(i0), p1 = SWZ(i0 + Q), p2 = SWZ(i0 + 2 * Q), p3 = SWZ(i0 + 3 * Q);
        float2 a = z[p0], b = z[p1], c = z[p2], d = z[p3];
        float t0x = a.x + c.x,  t0y = a.y + c.y;
        float t1x = a.x - c.x,  t1y = a.y - c.y;
        float t2x = b.x + d.x,  t2y = b.y + d.y;
        float t3x = b.x - d.x,  t3y = b.y - d.y;
        float2 w1 = twg[pos << (10 - LQ)];
        w1.y = -w1.y;  // conj
        float2 w2 = make_float2(w1.x * w1.x - w1.y * w1.y, 2.f * w1.x * w1.y);
        float2 w3 = make_float2(w1.x * w2.x - w1.y * w2.y, w1.x * w2.y + w1.y * w2.x);
        z[p0] = make_float2(t0x + t2x, t0y + t2y);
        float y1x = t1x - t3y, y1y = t1y + t3x;   // t1 + i*t3 (inverse)
        z[p1] = make_float2(y1x * w1.x - y1y * w1.y, y1x * w1.y + y1y * w1.x);
        float y2x = t0x - t2x, y2y = t0y - t2y;
        z[p2] = make_float2(y2x * w2.x - y2y * w2.y, y2x * w2.y + y2y * w2.x);
        float y3x = t1x + t3y, y3y = t1y - t3x;   // t1 - i*t3
        z[p3] = make_float2(y3x * w3.x - y3y * w3.y, y3x * w3.y + y3y * w3.x);
    }
}

#define W16C_INIT {1.f, 0.9238795325f, 0.7071067812f, 0.3826834324f, 0.f, \
                   -0.3826834324f, -0.7071067812f, -0.9238795325f, -1.f, -0.9238795325f}
#define W16S_INIT {0.f, -0.3826834324f, -0.7071067812f, -0.9238795325f, -1.f, \
                   -0.9238795325f, -0.7071067812f, -0.3826834324f, 0.f, 0.3826834324f}

// forward 16-pt DIT (digit-reversed in, natural out): stride-1 then stride-4.
__device__ __forceinline__ void fwd16_dit(float2* v) {
    #pragma unroll
    for (int g = 0; g < 4; ++g) {
        float2 a = v[4*g], b = v[4*g+1], c = v[4*g+2], d = v[4*g+3];
        float t0x = a.x + c.x, t0y = a.y + c.y, t1x = a.x - c.x, t1y = a.y - c.y;
        float t2x = b.x + d.x, t2y = b.y + d.y, t3x = b.x - d.x, t3y = b.y - d.y;
        v[4*g]   = make_float2(t0x + t2x, t0y + t2y);
        v[4*g+1] = make_float2(t1x + t3y, t1y - t3x);
        v[4*g+2] = make_float2(t0x - t2x, t0y - t2y);
        v[4*g+3] = make_float2(t1x - t3y, t1y + t3x);
    }
    const float WC[10] = W16C_INIT;
    const float WS[10] = W16S_INIT;
    #pragma unroll
    for (int m = 0; m < 4; ++m) {
        float2 a = v[m];
        float2 b0 = v[m+4], c0 = v[m+8], d0 = v[m+12];
        float2 b = make_float2(b0.x*WC[m]   - b0.y*WS[m],   b0.x*WS[m]   + b0.y*WC[m]);
        float2 c = make_float2(c0.x*WC[2*m] - c0.y*WS[2*m], c0.x*WS[2*m] + c0.y*WC[2*m]);
        float2 d = make_float2(d0.x*WC[3*m] - d0.y*WS[3*m], d0.x*WS[3*m] + d0.y*WC[3*m]);
        float t0x = a.x + c.x, t0y = a.y + c.y, t1x = a.x - c.x, t1y = a.y - c.y;
        float t2x = b.x + d.x, t2y = b.y + d.y, t3x = b.x - d.x, t3y = b.y - d.y;
        v[m]    = make_float2(t0x + t2x, t0y + t2y);
        v[m+4]  = make_float2(t1x + t3y, t1y - t3x);
        v[m+8]  = make_float2(t0x - t2x, t0y - t2y);
        v[m+12] = make_float2(t1x - t3y, t1y + t3x);
    }
}

// inverse 16-pt DIF (natural in, digit-reversed out): stride-4 then stride-1.
__device__ __forceinline__ void inv16_dif(float2* v) {
    const float WC[10] = W16C_INIT;
    const float WS[10] = W16S_INIT;
    #pragma unroll
    for (int m = 0; m < 4; ++m) {
        float2 a = v[m], b = v[m+4], c = v[m+8], d = v[m+12];
        float t0x = a.x + c.x, t0y = a.y + c.y, t1x = a.x - c.x, t1y = a.y - c.y;
        float t2x = b.x + d.x, t2y = b.y + d.y, t3x = b.x - d.x, t3y = b.y - d.y;
        float y1x = t1x - t3y, y1y = t1y + t3x;   // t1 + i*t3
        float y2x = t0x - t2x, y2y = t0y - t2y;
        float y3x = t1x + t3y, y3y = t1y - t3x;   // t1 - i*t3
        v[m]    = make_float2(t0x + t2x, t0y + t2y);
        // multiply by conj(W16^m): (x,y)*(wc,-ws) = (x*wc + y*ws, y*wc - x*ws)
        v[m+4]  = make_float2(y1x*WC[m]   + y1y*WS[m],   y1y*WC[m]   - y1x*WS[m]);
        v[m+8]  = make_float2(y2x*WC[2*m] + y2y*WS[2*m], y2y*WC[2*m] - y2x*WS[2*m]);
        v[m+12] = make_float2(y3x*WC[3*m] + y3y*WS[3*m], y3y*WC[3*m] - y3x*WS[3*m]);
    }
    #pragma unroll
    for (int g = 0; g < 4; ++g) {
        float2 a = v[4*g], b = v[4*g+1], c = v[4*g+2], d = v[4*g+3];
        float t0x = a.x + c.x, t0y = a.y + c.y, t1x = a.x - c.x, t1y = a.y - c.y;
        float t2x = b.x + d.x, t2y = b.y + d.y, t3x = b.x - d.x, t3y = b.y - d.y;
        v[4*g]   = make_float2(t0x + t2x, t0y + t2y);
        v[4*g+1] = make_float2(t1x - t3y, t1y + t3x);
        v[4*g+2] = make_float2(t0x - t2x, t0y - t2y);
        v[4*g+3] = make_float2(t1x + t3y, t1y - t3x);
    }
}

// One block per PAIR of lines (2m, 2m+1): packed complex FFT does both.
// Forward DIT (digit-reversed deposit -> natural spectrum); modulate natural;
// inverse DIF (natural -> digit-reversed time, gathered at output).
__global__ __launch_bounds__(256) void k_spectral(
        const float* __restrict__ xt,    // [B][D][N]
        const float* __restrict__ ag,    // [B][32784]
        const float* __restrict__ al,    // [B][80]
        const float* __restrict__ gate,  // [B][8]
        const float* __restrict__ bf_g, const float* __restrict__ bb_g,
        const float* __restrict__ bf_l, const float* __restrict__ bb_l,
        const float2* __restrict__ twg, const float* __restrict__ hanng,
        float* __restrict__ fused)       // [B][D][N]
{
    __shared__ float2 z[4096];   // 32 KB exactly, XOR-swizzled addressing
    int line0 = blockIdx.x * 2;   // b*768 + d0, d0 even
    int d0 = line0 % 768, b = line0 / 768;
    int h = d0 / HD_;             // both lines share h (HD=96 even)
    int t = threadIdx.x;

    // load both raw lines (16 contiguous n per thread each)
    const float* src0 = xt + (size_t)line0 * N_;
    const float* src1 = src0 + N_;
    float raw0[16], raw1[16];
    #pragma unroll
    for (int q = 0; q < 4; ++q) {
        float4 v0 = ((const float4*)src0)[t * 4 + q];
        float4 v1 = ((const float4*)src1)[t * 4 + q];
        raw0[q * 4 + 0] = v0.x; raw0[q * 4 + 1] = v0.y;
        raw0[q * 4 + 2] = v0.z; raw0[q * 4 + 3] = v0.w;
        raw1[q * 4 + 0] = v1.x; raw1[q * 4 + 1] = v1.y;
        raw1[q * 4 + 2] = v1.z; raw1[q * 4 + 3] = v1.w;
    }
    // deposit packed complex z = x0 + i*x1, Hann-windowed, at rev4 position (DIT)
    #pragma unroll
    for (int q = 0; q < 4; ++q) {
        float4 hw = ((const float4*)hanng)[t * 4 + q];
        int nb = t * 16 + q * 4;
        z[SWZ(rev4_12(nb + 0))] = make_float2(raw0[q*4+0] * hw.x, raw1[q*4+0] * hw.x);
        z[SWZ(rev4_12(nb + 1))] = make_float2(raw0[q*4+1] * hw.y, raw1[q*4+1] * hw.y);
        z[SWZ(rev4_12(nb + 2))] = make_float2(raw0[q*4+2] * hw.z, raw1[q*4+2] * hw.z);
        z[SWZ(rev4_12(nb + 3))] = make_float2(raw0[q*4+3] * hw.w, raw1[q*4+3] * hw.w);
    }

    // ---- local branch in registers (2 windows of 8 per thread, both lines) ----
    float alc = gate[b * 8 + h];
    const float* alb = al + b * 80;
    float effl_f[5], effl_b[5];
    #pragma unroll
    for (int f = 0; f < 5; ++f) {
        int idx = h * 5 + f;
        effl_f[f] = bf_l[idx] * (1.0f + alb[idx * 2]);
        effl_b[f] = bb_l[idx] + alb[idx * 2 + 1];
    }
    const float s8 = 0.3535533905932738f;  // 1/sqrt(8)
    const float c7 = 0.7071067811865476f;
    const float cosT[8] = {1.f, c7, 0.f, -c7, -1.f, -c7, 0.f, c7};
    const float sinT[8] = {0.f, c7, 1.f, c7, 0.f, -c7, -1.f, -c7};
    const float hl[8] = {0.f, 0.18825510f, 0.61126047f, 0.95048444f,
                         0.95048444f, 0.61126047f, 0.18825510f, 0.f};
    float xl0[16], xl1[16];
    #pragma unroll
    for (int ln = 0; ln < 2; ++ln) {
        float* rawp = ln ? raw1 : raw0;
        float* xlp  = ln ? xl1 : xl0;
        #pragma unroll
        for (int w2 = 0; w2 < 2; ++w2) {
            float xw[8];
            #pragma unroll
            for (int j = 0; j < 8; ++j) xw[j] = rawp[w2 * 8 + j] * hl[j];
            float Yr[5], Yi[5];
            #pragma unroll
            for (int f = 0; f < 5; ++f) {
                float fr = 0.f, fi = 0.f;
                #pragma unroll
                for (int j = 0; j < 8; ++j) {
                    int k8 = (f * j) & 7;
                    fr += xw[j] * cosT[k8];
                    fi -= xw[j] * sinT[k8];
                }
                fr *= s8; fi *= s8;
                float zr = fr * effl_f[f] + effl_b[f];
                float zi = fi * effl_f[f];
                float mag = sqrtf(zr * zr + zi * zi);
                float g = gelu_f(mag) * __builtin_amdgcn_rcpf(mag + 1e-6f);
                Yr[f] = zr * g; Yi[f] = zi * g;
            }
            #pragma unroll
            for (int j = 0; j < 8; ++j) {
                float acc = Yr[0] + Yr[4] * ((j & 1) ? -1.f : 1.f);
                #pragma unroll
                for (int f = 1; f < 4; ++f) {
                    int k8 = (f * j) & 7;
                    acc += 2.f * (Yr[f] * cosT[k8] - Yi[f] * sinT[k8]);
                }
                xlp[w2 * 8 + j] = acc * s8;
            }
        }
    }

    __syncthreads();
    // ---- forward DIT: 16-pt in registers (strides 1,4), then LDS Q=16..1024 ----
    {
        float2 v[16];
        #pragma unroll
        for (int i = 0; i < 16; ++i) v[i] = z[SWZ(t * 16 + i)];
        fwd16_dit(v);
        #pragma unroll
        for (int i = 0; i < 16; ++i) z[SWZ(t * 16 + i)] = v[i];
    }
    __syncthreads();
    dit_stage_f<4>(z, twg, t);  __syncthreads();
    dit_stage_f<6>(z, twg, t);  __syncthreads();
    dit_stage_f<8>(z, twg, t);  __syncthreads();
    dit_stage_f<10>(z, twg, t); __syncthreads();

    // Hermitian split + modulate + cgelu + re-pack, NATURAL order (conflict-free)
    const float inv64 = 1.0f / 64.0f;
    const float* agb = ag + (size_t)b * 32784;
    for (int k = t; k < 2048; k += 256) {
        int km = (4096 - k) & 4095;
        int pk = SWZ(k), pm = SWZ(km);
        float2 Z = z[pk], Z2 = z[pm];
        float X0r = 0.5f * (Z.x + Z2.x), X0i = 0.5f * (Z.y - Z2.y);
        float X1r = 0.5f * (Z.y + Z2.y), X1i = -0.5f * (Z.x - Z2.x);
        int idx = h * FG_ + k;
        float efff = bf_g[idx] * (1.0f + agb[idx * 2]);
        float effb = bb_g[idx] + agb[idx * 2 + 1];
        float z0r = X0r * inv64 * efff + effb, z0i = X0i * inv64 * efff;
        float m0 = sqrtf(z0r * z0r + z0i * z0i);
        float g0 = gelu_f(m0) * __builtin_amdgcn_rcpf(m0 + 1e-6f);
        float Y0r = z0r * g0, Y0i = z0i * g0;
        float z1r = X1r * inv64 * efff + effb, z1i = X1i * inv64 * efff;
        float m1 = sqrtf(z1r * z1r + z1i * z1i);
        float g1 = gelu_f(m1) * __builtin_amdgcn_rcpf(m1 + 1e-6f);
        float Y1r = z1r * g1, Y1i = z1i * g1;
        z[pk] = make_float2(Y0r - Y1i, Y0i + Y1r);
        if (k) z[pm] = make_float2(Y0r + Y1i, Y1r - Y0i);
    }
    if (t == 0) {  // Nyquist bin k=2048 (self-mirror; X0,X1 real)
        int pk = SWZ(2048);
        float2 Z = z[pk];
        int idx = h * FG_ + 2048;
        float efff = bf_g[idx] * (1.0f + agb[idx * 2]);
        float effb = bb_g[idx] + agb[idx * 2 + 1];
        float z0r = Z.x * inv64 * efff + effb;
        float m0 = fabsf(z0r);
        float Y0r = z0r * (gelu_f(m0) * __builtin_amdgcn_rcpf(m0 + 1e-6f));
        float z1r = Z.y * inv64 * efff + effb;
        float m1 = fabsf(z1r);
        float Y1r = z1r * (gelu_f(m1) * __builtin_amdgcn_rcpf(m1 + 1e-6f));
        z[pk] = make_float2(Y0r, Y1r);
    }
    __syncthreads();

    // ---- inverse DIF: LDS Q=1024..16, then 16-pt in registers (strides 4,1) ----
    dif_stage_i<10>(z, twg, t); __syncthreads();
    dif_stage_i<8>(z, twg, t);  __syncthreads();
    dif_stage_i<6>(z, twg, t);  __syncthreads();
    dif_stage_i<4>(z, twg, t);  __syncthreads();
    {
        float2 v[16];
        #pragma unroll
        for (int i = 0; i < 16; ++i) v[i] = z[SWZ(t * 16 + i)];
        inv16_dif(v);
        #pragma unroll
        for (int i = 0; i < 16; ++i) z[SWZ(t * 16 + i)] = v[i];
    }
    __syncthreads();

    // fuse and store both lines: y[n] sits at position rev4(n)
    float* dst0 = fused + (size_t)line0 * N_;
    float* dst1 = dst0 + N_;
    float one_m = 1.0f - alc;
    #pragma unroll
    for (int q = 0; q < 4; ++q) {
        int base = t * 16 + q * 4;
        float2 za = z[SWZ(rev4_12(base + 0))], zb = z[SWZ(rev4_12(base + 1))];
        float2 zc = z[SWZ(rev4_12(base + 2))], zd = z[SWZ(rev4_12(base + 3))];
        float4 v0 = make_float4(alc * za.x * inv64 + one_m * xl0[q * 4 + 0],
                                alc * zb.x * inv64 + one_m * xl0[q * 4 + 1],
                                alc * zc.x * inv64 + one_m * xl0[q * 4 + 2],
                                alc * zd.x * inv64 + one_m * xl0[q * 4 + 3]);
        float4 v1 = make_float4(alc * za.y * inv64 + one_m * xl1[q * 4 + 0],
                                alc * zb.y * inv64 + one_m * xl1[q * 4 + 1],
                                alc * zc.y * inv64 + one_m * xl1[q * 4 + 2],
                                alc * zd.y * inv64 + one_m * xl1[q * 4 + 3]);
        ((float4*)dst0)[t * 4 + q] = v0;
        ((float4*)dst1)[t * 4 + q] = v1;
    }
}

// out[b,n,d] = x[b,n,d] + fused[b,d,n]  (tiled transpose-add)
__global__ void k_addout(const float* __restrict__ fused, const float* __restrict__ x,
                         float* __restrict__ out) {
    __shared__ float tile[64][65];
    int d0 = blockIdx.x * 64, n0 = blockIdx.y * 64, b = blockIdx.z;
    int c = threadIdx.x & 63, r4 = threadIdx.x >> 6;
    for (int q = 0; q < 16; ++q) {
        int r = r4 * 16 + q;  // d-row
        tile[r][c] = fused[((size_t)b * D_ + d0 + r) * N_ + n0 + c];
    }
    __syncthreads();
    for (int q = 0; q < 16; ++q) {
        int r = r4 * 16 + q;  // n-row
        size_t o = ((size_t)b * N_ + n0 + r) * D_ + d0 + c;
        out[o] = x[o] + tile[c][r];
    }
}

extern "C" void kernel_launch(void* const* d_in, const int* in_sizes, int n_in,
                              void* d_out, int out_size, void* d_ws, size_t ws_size,
                              hipStream_t stream) {
    const float* x    = (const float*)d_in[0];
    const float* ln_w = (const float*)d_in[1];
    const float* ln_b = (const float*)d_in[2];
    const float* bf_g = (const float*)d_in[3];
    const float* bb_g = (const float*)d_in[4];
    const float* bf_l = (const float*)d_in[5];
    const float* bb_l = (const float*)d_in[6];
    const float* w1g  = (const float*)d_in[7];
    const float* b1g  = (const float*)d_in[8];
    const float* w2g  = (const float*)d_in[9];
    const float* b2g  = (const float*)d_in[10];
    const float* w1l  = (const float*)d_in[11];
    const float* b1l  = (const float*)d_in[12];
    const float* w2l  = (const float*)d_in[13];
    const float* b2l  = (const float*)d_in[14];
    const float* wf1  = (const float*)d_in[15];
    const float* bf1  = (const float*)d_in[16];
    const float* wf2  = (const float*)d_in[17];
    const float* bf2  = (const float*)d_in[18];
    float* out = (float*)d_out;

    char* ws = (char*)d_ws;
    const size_t big = (size_t)B_ * D_ * N_ * sizeof(float);  // ~100.7 MB
    float* XT  = (float*)ws; ws += big;
    float* FU  = (float*)ws; ws += big;   // fused output of spectral
    float* ctx = (float*)ws; ws += (size_t)B_ * D_ * 4;
    float* h1g = (float*)ws; ws += (size_t)B_ * 768 * 4;
    float* h1l = (float*)ws; ws += (size_t)B_ * 768 * 4;
    float* hf  = (float*)ws; ws += (size_t)B_ * 384 * 4;
    float* ag  = (float*)ws; ws += (size_t)B_ * 32784 * 4;
    float* alb = (float*)ws; ws += (size_t)B_ * 80 * 4;
    float* gat = (float*)ws; ws += (size_t)B_ * 8 * 4;
    float2* twg = (float2*)ws; ws += 2048 * sizeof(float2);
    float* hanng = (float*)ws; ws += 4096 * sizeof(float);
    // mu/rstd alias the head of FU: dead before k_spectral writes FU.
    float* mu   = FU;
    float* rstd = FU + 32768;

    k_init<<<129, 256, 0, stream>>>(b2g, b2l, b1g, b1l, twg, hanng, ctx, ag, alb,
                                    h1g, h1l);
    k_stats<<<8192, 256, 0, stream>>>(x, mu, rstd);
    k_lnT<<<dim3(12, 64, 8), 256, 0, stream>>>(x, mu, rstd, ln_w, ln_b, XT, ctx);
    k_mlp1<<<dim3(8, 9), 256, 0, stream>>>(ctx, w1g, w1l, wf1, bf1, h1g, h1l, hf);
    k_mlp2<<<dim3(129, 8), 256, 0, stream>>>(h1g, h1l, hf, w2g, w2l, wf2, bf2, ag, alb, gat);
    k_spectral<<<B_ * D_ / 2, 256, 0, stream>>>(XT, ag, alb, gat, bf_g, bb_g, bf_l, bb_l,
                                                twg, hanng, FU);
    k_addout<<<dim3(12, 64, 8), 256, 0, stream>>>(FU, x, out);
}

// Round 5
// 615.188 us; speedup vs baseline: 1.0159x; 1.0159x over previous
//
#include <hip/hip_runtime.h>
#include <math.h>

#define B_ 8
#define N_ 4096
#define D_ 768
#define H_ 8
#define HD_ 96
#define FG_ 2049
#define TWO_PI 6.283185307179586476925f
// XOR bank swizzle for float2 LDS array: bijective involution, no padding.
#define SWZ(i) ((i) ^ (((i) >> 4) & 15))

__device__ __forceinline__ float2 cmul(float2 a, float2 b) {
    return make_float2(a.x * b.x - a.y * b.y, a.x * b.y + a.y * b.x);
}

// Abramowitz-Stegun 7.1.26: |err| <= 1.5e-7, much cheaper than libm erff.
__device__ __forceinline__ float erf_fast(float x) {
    float ax = fabsf(x);
    float t = __builtin_amdgcn_rcpf(fmaf(0.3275911f, ax, 1.0f));
    float p = fmaf(fmaf(fmaf(fmaf(1.061405429f, t, -1.453152027f), t, 1.421413741f),
                        t, -0.284496736f), t, 0.254829592f) * t;
    float r = 1.0f - p * __expf(-ax * ax);
    return copysignf(r, x);
}

__device__ __forceinline__ float gelu_f(float x) {
    return 0.5f * x * (1.0f + erf_fast(x * 0.7071067811865475f));
}

// base-4 digit reversal of a 12-bit index (involution)
__device__ __forceinline__ int rev4_12(int x) {
    int r = (int)(__brev((unsigned)x) >> 20);
    return ((r & 0x555) << 1) | ((r >> 1) & 0x555);
}

// One-time init: twiddles, Hann, ctx zero, ag/al/h1g/h1l bias init.
__global__ void k_init(const float* __restrict__ b2g, const float* __restrict__ b2l,
                       const float* __restrict__ b1g, const float* __restrict__ b1l,
                       float2* __restrict__ twg, float* __restrict__ hanng,
                       float* __restrict__ ctx, float* __restrict__ ag,
                       float* __restrict__ al, float* __restrict__ h1g,
                       float* __restrict__ h1l) {
    int i = blockIdx.x * 256 + threadIdx.x;
    if (i < 2048) {
        float s, c;
        sincosf(-TWO_PI * (float)i / 4096.0f, &s, &c);
        twg[i] = make_float2(c, s);
    }
    if (i < 4096) hanng[i] = 0.5f - 0.5f * cosf(TWO_PI * (float)i / 4095.0f);
    if (i < B_ * D_) ctx[i] = 0.f;
    if (i < 768) {
        float vg = b1g[i], vl = b1l[i];
        for (int b = 0; b < B_; ++b) {
            h1g[b * 768 + i] = vg;
            h1l[b * 768 + i] = vl;
        }
    }
    const int CG = H_ * FG_ * 2;  // 32784
    if (i < CG) {
        float v = b2g[i];
        for (int b = 0; b < B_; ++b) ag[(size_t)b * CG + i] = v;
    } else if (i < CG + 80) {
        int cc = i - CG;
        float v = b2l[cc];
        for (int b = 0; b < B_; ++b) al[b * 80 + cc] = v;
    }
}

// Fused LayerNorm: per-64-row slab, pass1 stats (shuffle reduce), pass2
// normalize + transposed write [B][D][N] (L2-hot re-read) + ctx atomics.
__global__ __launch_bounds__(256) void k_lnT(const float* __restrict__ x,
                                             const float* __restrict__ lw,
                                             const float* __restrict__ lb,
                                             float* __restrict__ xt,
                                             float* __restrict__ ctx) {
    __shared__ float tile[64][65];
    __shared__ float csum[4][64];
    __shared__ float mus[64], rstds[64];
    int n0 = blockIdx.x * 64, b = blockIdx.y;
    int t = threadIdx.x;
    // ---- pass 1: stats. 4 threads per row, 192 cols each (48 float4). ----
    {
        int r = t >> 2, sub = t & 3;
        const float4* rowp = (const float4*)(x + ((size_t)(b * N_ + n0 + r)) * D_) + sub * 48;
        float s = 0.f, s2 = 0.f;
        #pragma unroll 4
        for (int i = 0; i < 48; ++i) {
            float4 v = rowp[i];
            s += v.x + v.y + v.z + v.w;
            s2 += v.x * v.x + v.y * v.y + v.z * v.z + v.w * v.w;
        }
        s += __shfl_xor(s, 1);  s += __shfl_xor(s, 2);
        s2 += __shfl_xor(s2, 1); s2 += __shfl_xor(s2, 2);
        if (sub == 0) {
            float m = s * (1.0f / 768.0f);
            mus[r] = m;
            rstds[r] = rsqrtf(s2 * (1.0f / 768.0f) - m * m + 1e-5f);
        }
    }
    __syncthreads();
    // ---- pass 2: 12 d-tiles of 64x64 ----
    int c = t & 63, r4 = t >> 6;
    for (int dt = 0; dt < 12; ++dt) {
        int d0 = dt * 64;
        float wv = lw[d0 + c], bv = lb[d0 + c];
        float partial = 0.f;
        #pragma unroll
        for (int q = 0; q < 16; ++q) {
            int r = r4 * 16 + q;
            float v = (x[((size_t)(b * N_ + n0 + r)) * D_ + d0 + c] - mus[r]) * rstds[r] * wv + bv;
            tile[r][c] = v;
            partial += v;
        }
        csum[r4][c] = partial;
        __syncthreads();
        if (r4 == 0)
            atomicAdd(ctx + b * D_ + d0 + c,
                      (csum[0][c] + csum[1][c] + csum[2][c] + csum[3][c]) * (1.0f / 4096.0f));
        #pragma unroll
        for (int q = 0; q < 16; ++q) {
            int r = r4 * 16 + q;  // d-row
            xt[((size_t)b * D_ + d0 + r) * N_ + n0 + c] = tile[c][r];
        }
        __syncthreads();
    }
}

// Split-K pre-activation MLP1: h1g/h1l += ctx@w1 chunk (bias pre-init in k_init,
// gelu applied in k_mlp2 staging). hf computed full-depth by dedicated blocks.
__global__ void k_mlp1(const float* __restrict__ ctx,
                       const float* __restrict__ w1g, const float* __restrict__ w1l,
                       const float* __restrict__ wf1, const float* __restrict__ bf1,
                       float* __restrict__ h1g, float* __restrict__ h1l,
                       float* __restrict__ hf) {
    int t = threadIdx.x, xb = blockIdx.x, y = blockIdx.y;
    float acc[B_];
    #pragma unroll
    for (int b = 0; b < B_; ++b) acc[b] = 0.f;
    if (y < 8) {
        int c = xb * 256 + t;
        if (c >= 1536) return;
        const float* w = (c < 768) ? w1g : w1l;
        float* out = (c < 768) ? h1g : h1l;
        int cc = (c < 768) ? c : c - 768;
        int d0 = y * 96;
        for (int d = 0; d < 96; ++d) {
            float wv = w[(size_t)(d0 + d) * 768 + cc];
            #pragma unroll
            for (int b = 0; b < B_; ++b) acc[b] += ctx[b * 768 + d0 + d] * wv;
        }
        for (int b = 0; b < B_; ++b) atomicAdd(out + b * 768 + cc, acc[b]);
    } else {
        if (xb < 6) return;
        int cc = (xb - 6) * 256 + t;
        if (cc >= 384) return;
        for (int d = 0; d < 768; ++d) {
            float wv = wf1[(size_t)d * 384 + cc];
            #pragma unroll
            for (int b = 0; b < B_; ++b) acc[b] += ctx[b * 768 + d] * wv;
        }
        float bv = bf1[cc];
        for (int b = 0; b < B_; ++b) hf[b * 384 + cc] = gelu_f(acc[b] + bv);
    }
}

// split-K (8 chunks of 96): ag += gelu(h1g)@w2g chunk; al += gelu(h1l)@w2l; gate.
__global__ void k_mlp2(const float* __restrict__ h1g, const float* __restrict__ h1l,
                       const float* __restrict__ hf,
                       const float* __restrict__ w2g, const float* __restrict__ w2l,
                       const float* __restrict__ wf2, const float* __restrict__ bf2,
                       float* __restrict__ ag, float* __restrict__ al, float* __restrict__ gate) {
    int kc = blockIdx.y;       // 0..7
    int d0 = kc * 96;
    __shared__ float lg[B_ * 96];
    __shared__ float ll[B_ * 96];
    for (int i = threadIdx.x; i < B_ * 96; i += 256) {
        int bb = i / 96, dd = i % 96;
        lg[i] = gelu_f(h1g[bb * 768 + d0 + dd]);
        ll[i] = gelu_f(h1l[bb * 768 + d0 + dd]);
    }
    __syncthreads();
    int c = blockIdx.x * 256 + threadIdx.x;
    const int CG = H_ * FG_ * 2;  // 32784
    float acc[B_];
    #pragma unroll
    for (int b = 0; b < B_; ++b) acc[b] = 0.f;
    if (c < CG) {
        for (int d = 0; d < 96; ++d) {
            float wv = w2g[(size_t)(d0 + d) * CG + c];
            #pragma unroll
            for (int b = 0; b < B_; ++b) acc[b] += lg[b * 96 + d] * wv;
        }
        for (int b = 0; b < B_; ++b) atomicAdd(ag + (size_t)b * CG + c, acc[b]);
    } else if (c < CG + 80) {
        int cc = c - CG;
        for (int d = 0; d < 96; ++d) {
            float wv = w2l[(d0 + d) * 80 + cc];
            #pragma unroll
            for (int b = 0; b < B_; ++b) acc[b] += ll[b * 96 + d] * wv;
        }
        for (int b = 0; b < B_; ++b) atomicAdd(al + b * 80 + cc, acc[b]);
    } else if (c < CG + 88 && kc == 0) {
        int cc = c - CG - 80;
        for (int d = 0; d < 384; ++d) {
            float wv = wf2[d * 8 + cc];
            #pragma unroll
            for (int b = 0; b < B_; ++b) acc[b] += hf[b * 384 + d] * wv;
        }
        for (int b = 0; b < B_; ++b)
            gate[b * 8 + cc] = 1.0f / (1.0f + expf(-(acc[b] + bf2[cc])));
    }
}

// ---- FUSED radix-4 pair, FORWARD DIT: stages (Q, 4Q) in one LDS round-trip.
// Thread owns 16 elements {base + a*Q + b*4Q}; base = (t>>LQ)*16Q + (t&(Q-1)).
template<int LQ>
__device__ __forceinline__ void dit_pair_f(float2* z, const float2* __restrict__ twg, int t) {
    const int Q = 1 << LQ;
    int lo = t & (Q - 1);
    int base = ((t >> LQ) << (LQ + 4)) + lo;
    float2 v[16];   // v[b*4 + a]
    #pragma unroll
    for (int b = 0; b < 4; ++b)
        #pragma unroll
        for (int a = 0; a < 4; ++a)
            v[b * 4 + a] = z[SWZ(base + (b << (LQ + 2)) + (a << LQ))];
    // stage Q: one twiddle set for all 4 b-butterflies (pos = lo)
    {
        float2 w1 = twg[lo << (10 - LQ)];
        float2 w2 = cmul(w1, w1), w3 = cmul(w1, w2);
        #pragma unroll
        for (int b = 0; b < 4; ++b) {
            float2 A = v[b*4+0], Bv = cmul(v[b*4+1], w1);
            float2 C = cmul(v[b*4+2], w2), Dv = cmul(v[b*4+3], w3);
            float t0x = A.x + C.x,  t0y = A.y + C.y;
            float t1x = A.x - C.x,  t1y = A.y - C.y;
            float t2x = Bv.x + Dv.x, t2y = Bv.y + Dv.y;
            float t3x = Bv.x - Dv.x, t3y = Bv.y - Dv.y;
            v[b*4+0] = make_float2(t0x + t2x, t0y + t2y);
            v[b*4+1] = make_float2(t1x + t3y, t1y - t3x);
            v[b*4+2] = make_float2(t0x - t2x, t0y - t2y);
            v[b*4+3] = make_float2(t1x - t3y, t1y + t3x);
        }
    }
    // stage 4Q: pos4 = a*Q + lo (one twiddle set per a)
    #pragma unroll
    for (int a = 0; a < 4; ++a) {
        float2 u1 = twg[(a * Q + lo) << (8 - LQ)];
        float2 u2 = cmul(u1, u1), u3 = cmul(u1, u2);
        float2 A = v[0*4+a], Bv = cmul(v[1*4+a], u1);
        float2 C = cmul(v[2*4+a], u2), Dv = cmul(v[3*4+a], u3);
        float t0x = A.x + C.x,  t0y = A.y + C.y;
        float t1x = A.x - C.x,  t1y = A.y - C.y;
        float t2x = Bv.x + Dv.x, t2y = Bv.y + Dv.y;
        float t3x = Bv.x - Dv.x, t3y = Bv.y - Dv.y;
        v[0*4+a] = make_float2(t0x + t2x, t0y + t2y);
        v[1*4+a] = make_float2(t1x + t3y, t1y - t3x);
        v[2*4+a] = make_float2(t0x - t2x, t0y - t2y);
        v[3*4+a] = make_float2(t1x - t3y, t1y + t3x);
    }
    #pragma unroll
    for (int b = 0; b < 4; ++b)
        #pragma unroll
        for (int a = 0; a < 4; ++a)
            z[SWZ(base + (b << (LQ + 2)) + (a << LQ))] = v[b * 4 + a];
}

// ---- FUSED radix-4 pair, INVERSE DIF: stages (4Q, Q) in one LDS round-trip.
template<int LQ>
__device__ __forceinline__ void dif_pair_i(float2* z, const float2* __restrict__ twg, int t) {
    const int Q = 1 << LQ;
    int lo = t & (Q - 1);
    int base = ((t >> LQ) << (LQ + 4)) + lo;
    float2 v[16];   // v[b*4 + a]
    #pragma unroll
    for (int b = 0; b < 4; ++b)
        #pragma unroll
        for (int a = 0; a < 4; ++a)
            v[b * 4 + a] = z[SWZ(base + (b << (LQ + 2)) + (a << LQ))];
    // stage 4Q: combine over b for each a; conj twiddles on outputs (pos4 = a*Q+lo)
    #pragma unroll
    for (int a = 0; a < 4; ++a) {
        float2 A = v[0*4+a], Bv = v[1*4+a], C = v[2*4+a], Dv = v[3*4+a];
        float t0x = A.x + C.x,  t0y = A.y + C.y;
        float t1x = A.x - C.x,  t1y = A.y - C.y;
        float t2x = Bv.x + Dv.x, t2y = Bv.y + Dv.y;
        float t3x = Bv.x - Dv.x, t3y = Bv.y - Dv.y;
        float2 u1 = twg[(a * Q + lo) << (8 - LQ)];
        u1.y = -u1.y;
        float2 u2 = cmul(u1, u1), u3 = cmul(u1, u2);
        v[0*4+a] = make_float2(t0x + t2x, t0y + t2y);
        v[1*4+a] = cmul(make_float2(t1x - t3y, t1y + t3x), u1);
        v[2*4+a] = cmul(make_float2(t0x - t2x, t0y - t2y), u2);
        v[3*4+a] = cmul(make_float2(t1x + t3y, t1y - t3x), u3);
    }
    // stage Q: combine over a for each b; conj twiddles on outputs (pos = lo)
    {
        float2 w1 = twg[lo << (10 - LQ)];
        w1.y = -w1.y;
        float2 w2 = cmul(w1, w1), w3 = cmul(w1, w2);
        #pragma unroll
        for (int b = 0; b < 4; ++b) {
            float2 A = v[b*4+0], Bv = v[b*4+1], C = v[b*4+2], Dv = v[b*4+3];
            float t0x = A.x + C.x,  t0y = A.y + C.y;
            float t1x = A.x - C.x,  t1y = A.y - C.y;
            float t2x = Bv.x + Dv.x, t2y = Bv.y + Dv.y;
            float t3x = Bv.x - Dv.x, t3y = Bv.y - Dv.y;
            v[b*4+0] = make_float2(t0x + t2x, t0y + t2y);
            v[b*4+1] = cmul(make_float2(t1x - t3y, t1y + t3x), w1);
            v[b*4+2] = cmul(make_float2(t0x - t2x, t0y - t2y), w2);
            v[b*4+3] = cmul(make_float2(t1x + t3y, t1y - t3x), w3);
        }
    }
    #pragma unroll
    for (int b = 0; b < 4; ++b)
        #pragma unroll
        for (int a = 0; a < 4; ++a)
            z[SWZ(base + (b << (LQ + 2)) + (a << LQ))] = v[b * 4 + a];
}

#define W16C_INIT {1.f, 0.9238795325f, 0.7071067812f, 0.3826834324f, 0.f, \
                   -0.3826834324f, -0.7071067812f, -0.9238795325f, -1.f, -0.9238795325f}
#define W16S_INIT {0.f, -0.3826834324f, -0.7071067812f, -0.9238795325f, -1.f, \
                   -0.9238795325f, -0.7071067812f, -0.3826834324f, 0.f, 0.3826834324f}

// forward 16-pt DIT (digit-reversed in, natural out): stride-1 then stride-4.
__device__ __forceinline__ void fwd16_dit(float2* v) {
    #pragma unroll
    for (int g = 0; g < 4; ++g) {
        float2 a = v[4*g], b = v[4*g+1], c = v[4*g+2], d = v[4*g+3];
        float t0x = a.x + c.x, t0y = a.y + c.y, t1x = a.x - c.x, t1y = a.y - c.y;
        float t2x = b.x + d.x, t2y = b.y + d.y, t3x = b.x - d.x, t3y = b.y - d.y;
        v[4*g]   = make_float2(t0x + t2x, t0y + t2y);
        v[4*g+1] = make_float2(t1x + t3y, t1y - t3x);
        v[4*g+2] = make_float2(t0x - t2x, t0y - t2y);
        v[4*g+3] = make_float2(t1x - t3y, t1y + t3x);
    }
    const float WC[10] = W16C_INIT;
    const float WS[10] = W16S_INIT;
    #pragma unroll
    for (int m = 0; m < 4; ++m) {
        float2 a = v[m];
        float2 b0 = v[m+4], c0 = v[m+8], d0 = v[m+12];
        float2 b = make_float2(b0.x*WC[m]   - b0.y*WS[m],   b0.x*WS[m]   + b0.y*WC[m]);
        float2 c = make_float2(c0.x*WC[2*m] - c0.y*WS[2*m], c0.x*WS[2*m] + c0.y*WC[2*m]);
        float2 d = make_float2(d0.x*WC[3*m] - d0.y*WS[3*m], d0.x*WS[3*m] + d0.y*WC[3*m]);
        float t0x = a.x + c.x, t0y = a.y + c.y, t1x = a.x - c.x, t1y = a.y - c.y;
        float t2x = b.x + d.x, t2y = b.y + d.y, t3x = b.x - d.x, t3y = b.y - d.y;
        v[m]    = make_float2(t0x + t2x, t0y + t2y);
        v[m+4]  = make_float2(t1x + t3y, t1y - t3x);
        v[m+8]  = make_float2(t0x - t2x, t0y - t2y);
        v[m+12] = make_float2(t1x - t3y, t1y + t3x);
    }
}

// inverse 16-pt DIF (natural in, digit-reversed out): stride-4 then stride-1.
__device__ __forceinline__ void inv16_dif(float2* v) {
    const float WC[10] = W16C_INIT;
    const float WS[10] = W16S_INIT;
    #pragma unroll
    for (int m = 0; m < 4; ++m) {
        float2 a = v[m], b = v[m+4], c = v[m+8], d = v[m+12];
        float t0x = a.x + c.x, t0y = a.y + c.y, t1x = a.x - c.x, t1y = a.y - c.y;
        float t2x = b.x + d.x, t2y = b.y + d.y, t3x = b.x - d.x, t3y = b.y - d.y;
        float y1x = t1x - t3y, y1y = t1y + t3x;   // t1 + i*t3
        float y2x = t0x - t2x, y2y = t0y - t2y;
        float y3x = t1x + t3y, y3y = t1y - t3x;   // t1 - i*t3
        v[m]    = make_float2(t0x + t2x, t0y + t2y);
        v[m+4]  = make_float2(y1x*WC[m]   + y1y*WS[m],   y1y*WC[m]   - y1x*WS[m]);
        v[m+8]  = make_float2(y2x*WC[2*m] + y2y*WS[2*m], y2y*WC[2*m] - y2x*WS[2*m]);
        v[m+12] = make_float2(y3x*WC[3*m] + y3y*WS[3*m], y3y*WC[3*m] - y3x*WS[3*m]);
    }
    #pragma unroll
    for (int g = 0; g < 4; ++g) {
        float2 a = v[4*g], b = v[4*g+1], c = v[4*g+2], d = v[4*g+3];
        float t0x = a.x + c.x, t0y = a.y + c.y, t1x = a.x - c.x, t1y = a.y - c.y;
        float t2x = b.x + d.x, t2y = b.y + d.y, t3x = b.x - d.x, t3y = b.y - d.y;
        v[4*g]   = make_float2(t0x + t2x, t0y + t2y);
        v[4*g+1] = make_float2(t1x - t3y, t1y + t3x);
        v[4*g+2] = make_float2(t0x - t2x, t0y - t2y);
        v[4*g+3] = make_float2(t1x + t3y, t1y - t3x);
    }
}

// One block per PAIR of lines (2m, 2m+1): packed complex FFT does both.
__global__ __launch_bounds__(256) void k_spectral(
        const float* __restrict__ xt,    // [B][D][N]
        const float* __restrict__ ag,    // [B][32784]
        const float* __restrict__ al,    // [B][80]
        const float* __restrict__ gate,  // [B][8]
        const float* __restrict__ bf_g, const float* __restrict__ bb_g,
        const float* __restrict__ bf_l, const float* __restrict__ bb_l,
        const float2* __restrict__ twg, const float* __restrict__ hanng,
        float* __restrict__ fused)       // [B][D][N]
{
    __shared__ float2 z[4096];   // 32 KB exactly, XOR-swizzled addressing
    int line0 = blockIdx.x * 2;   // b*768 + d0, d0 even
    int d0 = line0 % 768, b = line0 / 768;
    int h = d0 / HD_;             // both lines share h (HD=96 even)
    int t = threadIdx.x;

    // load both raw lines (16 contiguous n per thread each)
    const float* src0 = xt + (size_t)line0 * N_;
    const float* src1 = src0 + N_;
    float raw0[16], raw1[16];
    #pragma unroll
    for (int q = 0; q < 4; ++q) {
        float4 v0 = ((const float4*)src0)[t * 4 + q];
        float4 v1 = ((const float4*)src1)[t * 4 + q];
        raw0[q * 4 + 0] = v0.x; raw0[q * 4 + 1] = v0.y;
        raw0[q * 4 + 2] = v0.z; raw0[q * 4 + 3] = v0.w;
        raw1[q * 4 + 0] = v1.x; raw1[q * 4 + 1] = v1.y;
        raw1[q * 4 + 2] = v1.z; raw1[q * 4 + 3] = v1.w;
    }
    // deposit packed complex z = x0 + i*x1, Hann-windowed, at rev4 position (DIT)
    #pragma unroll
    for (int q = 0; q < 4; ++q) {
        float4 hw = ((const float4*)hanng)[t * 4 + q];
        int nb = t * 16 + q * 4;
        z[SWZ(rev4_12(nb + 0))] = make_float2(raw0[q*4+0] * hw.x, raw1[q*4+0] * hw.x);
        z[SWZ(rev4_12(nb + 1))] = make_float2(raw0[q*4+1] * hw.y, raw1[q*4+1] * hw.y);
        z[SWZ(rev4_12(nb + 2))] = make_float2(raw0[q*4+2] * hw.z, raw1[q*4+2] * hw.z);
        z[SWZ(rev4_12(nb + 3))] = make_float2(raw0[q*4+3] * hw.w, raw1[q*4+3] * hw.w);
    }

    // ---- local branch: 8-pt real FFT per window (Hann(8) zeros at j=0,7) ----
    float alc = gate[b * 8 + h];
    const float* alb = al + b * 80;
    const float s8 = 0.3535533905932738f;  // 1/sqrt(8)
    const float c7 = 0.7071067811865476f;
    float sfl[5], effl_b[5];
    #pragma unroll
    for (int f = 0; f < 5; ++f) {
        int idx = h * 5 + f;
        sfl[f] = bf_l[idx] * (1.0f + alb[idx * 2]) * s8;   // s8 folded in
        effl_b[f] = bb_l[idx] + alb[idx * 2 + 1];
    }
    const float H1 = 0.18825510f, H2 = 0.61126047f, H3 = 0.95048444f;
    float xl0[16], xl1[16];
    #pragma unroll
    for (int ln = 0; ln < 2; ++ln) {
        float* rawp = ln ? raw1 : raw0;
        float* xlp  = ln ? xl1 : xl0;
        #pragma unroll
        for (int w2 = 0; w2 < 2; ++w2) {
            const float* r = rawp + w2 * 8;
            float x1 = r[1] * H1, x2 = r[2] * H2, x3 = r[3] * H3;
            float x4 = r[4] * H3, x5 = r[5] * H2, x6 = r[6] * H1;
            // forward rfft8 (x0 = x7 = 0)
            float s26 = x2 + x6, d26 = x2 - x6;
            float s15 = x1 + x5, d15 = x1 - x5;
            float E0 = x4 + s26, E2 = x4 - s26;
            float E1r = -x4, E1i = -d26;
            float O0 = s15 + x3, O2 = s15 - x3;
            float O1r = d15, O1i = -x3;
            float X0 = E0 + O0;
            float X4 = E0 - O0;
            float X2r = E2, X2i = -O2;
            float pp = c7 * (O1r + O1i), qq = c7 * (O1i - O1r);
            float X1r = E1r + pp, X1i = E1i + qq;
            float X3r = E1r - pp, X3i = qq - E1i;
            // modulate + cgelu per bin
            float Y0r, Y1r, Y1i, Y2r, Y2i, Y3r, Y3i, Y4r;
            {
                float zr = X0 * sfl[0] + effl_b[0];
                float m = fabsf(zr);
                Y0r = zr * (gelu_f(m) * __builtin_amdgcn_rcpf(m + 1e-6f));
            }
            {
                float zr = X1r * sfl[1] + effl_b[1], zi = X1i * sfl[1];
                float m = sqrtf(zr * zr + zi * zi);
                float g = gelu_f(m) * __builtin_amdgcn_rcpf(m + 1e-6f);
                Y1r = zr * g; Y1i = zi * g;
            }
            {
                float zr = X2r * sfl[2] + effl_b[2], zi = X2i * sfl[2];
                float m = sqrtf(zr * zr + zi * zi);
                float g = gelu_f(m) * __builtin_amdgcn_rcpf(m + 1e-6f);
                Y2r = zr * g; Y2i = zi * g;
            }
            {
                float zr = X3r * sfl[3] + effl_b[3], zi = X3i * sfl[3];
                float m = sqrtf(zr * zr + zi * zi);
                float g = gelu_f(m) * __builtin_amdgcn_rcpf(m + 1e-6f);
                Y3r = zr * g; Y3i = zi * g;
            }
            {
                float zr = X4 * sfl[4] + effl_b[4];
                float m = fabsf(zr);
                Y4r = zr * (gelu_f(m) * __builtin_amdgcn_rcpf(m + 1e-6f));
            }
            // inverse rfft8 (split): y[j] = c7 * ebar_j
            float iE0 = 0.5f * (Y0r + Y4r), iO0 = 0.5f * (Y0r - Y4r);
            float iE2 = Y2r, iO2 = -Y2i;
            float iE1r = 0.5f * (Y1r + Y3r), iE1i = 0.5f * (Y1i - Y3i);
            float Pr = 0.5f * (Y1r - Y3r), Pi = 0.5f * (Y1i + Y3i);
            float iO1r = c7 * (Pr - Pi), iO1i = c7 * (Pr + Pi);
            float ae = iE0 + iE2, be = iE0 - iE2;
            float ao = iO0 + iO2, bo = iO0 - iO2;
            xlp[w2*8 + 0] = c7 * (ae + 2.f * iE1r);
            xlp[w2*8 + 2] = c7 * (be - 2.f * iE1i);
            xlp[w2*8 + 4] = c7 * (ae - 2.f * iE1r);
            xlp[w2*8 + 6] = c7 * (be + 2.f * iE1i);
            xlp[w2*8 + 1] = c7 * (ao + 2.f * iO1r);
            xlp[w2*8 + 3] = c7 * (bo - 2.f * iO1i);
            xlp[w2*8 + 5] = c7 * (ao - 2.f * iO1r);
            xlp[w2*8 + 7] = c7 * (bo + 2.f * iO1i);
        }
    }

    __syncthreads();
    // ---- forward DIT: 16-pt in registers, then 2 fused LDS pairs ----
    {
        float2 v[16];
        #pragma unroll
        for (int i = 0; i < 16; ++i) v[i] = z[SWZ(t * 16 + i)];
        fwd16_dit(v);
        #pragma unroll
        for (int i = 0; i < 16; ++i) z[SWZ(t * 16 + i)] = v[i];
    }
    __syncthreads();
    dit_pair_f<4>(z, twg, t);  __syncthreads();   // stages Q=16, 64
    dit_pair_f<8>(z, twg, t);  __syncthreads();   // stages Q=256, 1024

    // Hermitian split + modulate + cgelu + re-pack, NATURAL order
    const float inv64 = 1.0f / 64.0f;
    const float* agb = ag + (size_t)b * 32784;
    for (int k = t; k < 2048; k += 256) {
        int km = (4096 - k) & 4095;
        int pk = SWZ(k), pm = SWZ(km);
        float2 Z = z[pk], Z2 = z[pm];
        float X0r = 0.5f * (Z.x + Z2.x), X0i = 0.5f * (Z.y - Z2.y);
        float X1r = 0.5f * (Z.y + Z2.y), X1i = -0.5f * (Z.x - Z2.x);
        int idx = h * FG_ + k;
        float efff = bf_g[idx] * (1.0f + agb[idx * 2]);
        float effb = bb_g[idx] + agb[idx * 2 + 1];
        float z0r = X0r * inv64 * efff + effb, z0i = X0i * inv64 * efff;
        float m0 = sqrtf(z0r * z0r + z0i * z0i);
        float g0 = gelu_f(m0) * __builtin_amdgcn_rcpf(m0 + 1e-6f);
        float Y0r = z0r * g0, Y0i = z0i * g0;
        float z1r = X1r * inv64 * efff + effb, z1i = X1i * inv64 * efff;
        float m1 = sqrtf(z1r * z1r + z1i * z1i);
        float g1 = gelu_f(m1) * __builtin_amdgcn_rcpf(m1 + 1e-6f);
        float Y1r = z1r * g1, Y1i = z1i * g1;
        z[pk] = make_float2(Y0r - Y1i, Y0i + Y1r);
        if (k) z[pm] = make_float2(Y0r + Y1i, Y1r - Y0i);
    }
    if (t == 0) {  // Nyquist bin k=2048 (self-mirror; X0,X1 real)
        int pk = SWZ(2048);
        float2 Z = z[pk];
        int idx = h * FG_ + 2048;
        float efff = bf_g[idx] * (1.0f + agb[idx * 2]);
        float effb = bb_g[idx] + agb[idx * 2 + 1];
        float z0r = Z.x * inv64 * efff + effb;
        float m0 = fabsf(z0r);
        float Y0r = z0r * (gelu_f(m0) * __builtin_amdgcn_rcpf(m0 + 1e-6f));
        float z1r = Z.y * inv64 * efff + effb;
        float m1 = fabsf(z1r);
        float Y1r = z1r * (gelu_f(m1) * __builtin_amdgcn_rcpf(m1 + 1e-6f));
        z[pk] = make_float2(Y0r, Y1r);
    }
    __syncthreads();

    // ---- inverse DIF: 2 fused LDS pairs, then 16-pt in registers ----
    dif_pair_i<8>(z, twg, t);  __syncthreads();   // stages Q=1024, 256
    dif_pair_i<4>(z, twg, t);  __syncthreads();   // stages Q=64, 16
    {
        float2 v[16];
        #pragma unroll
        for (int i = 0; i < 16; ++i) v[i] = z[SWZ(t * 16 + i)];
        inv16_dif(v);
        #pragma unroll
        for (int i = 0; i < 16; ++i) z[SWZ(t * 16 + i)] = v[i];
    }
    __syncthreads();

    // fuse and store both lines: y[n] sits at position rev4(n)
    float* dst0 = fused + (size_t)line0 * N_;
    float* dst1 = dst0 + N_;
    float one_m = 1.0f - alc;
    #pragma unroll
    for (int q = 0; q < 4; ++q) {
        int base = t * 16 + q * 4;
        float2 za = z[SWZ(rev4_12(base + 0))], zb = z[SWZ(rev4_12(base + 1))];
        float2 zc = z[SWZ(rev4_12(base + 2))], zd = z[SWZ(rev4_12(base + 3))];
        float4 v0 = make_float4(alc * za.x * inv64 + one_m * xl0[q * 4 + 0],
                                alc * zb.x * inv64 + one_m * xl0[q * 4 + 1],
                                alc * zc.x * inv64 + one_m * xl0[q * 4 + 2],
                                alc * zd.x * inv64 + one_m * xl0[q * 4 + 3]);
        float4 v1 = make_float4(alc * za.y * inv64 + one_m * xl1[q * 4 + 0],
                                alc * zb.y * inv64 + one_m * xl1[q * 4 + 1],
                                alc * zc.y * inv64 + one_m * xl1[q * 4 + 2],
                                alc * zd.y * inv64 + one_m * xl1[q * 4 + 3]);
        ((float4*)dst0)[t * 4 + q] = v0;
        ((float4*)dst1)[t * 4 + q] = v1;
    }
}

// out[b,n,d] = x[b,n,d] + fused[b,d,n]  (tiled transpose-add)
__global__ void k_addout(const float* __restrict__ fused, const float* __restrict__ x,
                         float* __restrict__ out) {
    __shared__ float tile[64][65];
    int d0 = blockIdx.x * 64, n0 = blockIdx.y * 64, b = blockIdx.z;
    int c = threadIdx.x & 63, r4 = threadIdx.x >> 6;
    for (int q = 0; q < 16; ++q) {
        int r = r4 * 16 + q;  // d-row
        tile[r][c] = fused[((size_t)b * D_ + d0 + r) * N_ + n0 + c];
    }
    __syncthreads();
    for (int q = 0; q < 16; ++q) {
        int r = r4 * 16 + q;  // n-row
        size_t o = ((size_t)b * N_ + n0 + r) * D_ + d0 + c;
        out[o] = x[o] + tile[c][r];
    }
}

extern "C" void kernel_launch(void* const* d_in, const int* in_sizes, int n_in,
                              void* d_out, int out_size, void* d_ws, size_t ws_size,
                              hipStream_t stream) {
    const float* x    = (const float*)d_in[0];
    const float* ln_w = (const float*)d_in[1];
    const float* ln_b = (const float*)d_in[2];
    const float* bf_g = (const float*)d_in[3];
    const float* bb_g = (const float*)d_in[4];
    const float* bf_l = (const float*)d_in[5];
    const float* bb_l = (const float*)d_in[6];
    const float* w1g  = (const float*)d_in[7];
    const float* b1g  = (const float*)d_in[8];
    const float* w2g  = (const float*)d_in[9];
    const float* b2g  = (const float*)d_in[10];
    const float* w1l  = (const float*)d_in[11];
    const float* b1l  = (const float*)d_in[12];
    const float* w2l  = (const float*)d_in[13];
    const float* b2l  = (const float*)d_in[14];
    const float* wf1  = (const float*)d_in[15];
    const float* bf1  = (const float*)d_in[16];
    const float* wf2  = (const float*)d_in[17];
    const float* bf2  = (const float*)d_in[18];
    float* out = (float*)d_out;

    char* ws = (char*)d_ws;
    const size_t big = (size_t)B_ * D_ * N_ * sizeof(float);  // ~100.7 MB
    float* XT  = (float*)ws; ws += big;
    float* FU  = (float*)ws; ws += big;   // fused output of spectral
    float* ctx = (float*)ws; ws += (size_t)B_ * D_ * 4;
    float* h1g = (float*)ws; ws += (size_t)B_ * 768 * 4;
    float* h1l = (float*)ws; ws += (size_t)B_ * 768 * 4;
    float* hf  = (float*)ws; ws += (size_t)B_ * 384 * 4;
    float* ag  = (float*)ws; ws += (size_t)B_ * 32784 * 4;
    float* alb = (float*)ws; ws += (size_t)B_ * 80 * 4;
    float* gat = (float*)ws; ws += (size_t)B_ * 8 * 4;
    float2* twg = (float2*)ws; ws += 2048 * sizeof(float2);
    float* hanng = (float*)ws; ws += 4096 * sizeof(float);

    k_init<<<129, 256, 0, stream>>>(b2g, b2l, b1g, b1l, twg, hanng, ctx, ag, alb,
                                    h1g, h1l);
    k_lnT<<<dim3(64, 8), 256, 0, stream>>>(x, ln_w, ln_b, XT, ctx);
    k_mlp1<<<dim3(8, 9), 256, 0, stream>>>(ctx, w1g, w1l, wf1, bf1, h1g, h1l, hf);
    k_mlp2<<<dim3(129, 8), 256, 0, stream>>>(h1g, h1l, hf, w2g, w2l, wf2, bf2, ag, alb, gat);
    k_spectral<<<B_ * D_ / 2, 256, 0, stream>>>(XT, ag, alb, gat, bf_g, bb_g, bf_l, bb_l,
                                                twg, hanng, FU);
    k_addout<<<dim3(12, 64, 8), 256, 0, stream>>>(FU, x, out);
}